// Round 5
// baseline (433.934 us; speedup 1.0000x reference)
//
#include <hip/hip_runtime.h>
#include <stdint.h>

typedef unsigned short u16;
typedef short s16x8 __attribute__((ext_vector_type(8)));
typedef unsigned short u16x8 __attribute__((ext_vector_type(8)));
typedef float f32x4 __attribute__((ext_vector_type(4)));

#define GLD16(g, l) __builtin_amdgcn_global_load_lds( \
    (const __attribute__((address_space(1))) uint32_t*)(g), \
    (__attribute__((address_space(3))) uint32_t*)(l), 16, 0, 0)

__device__ __forceinline__ u16 f2bf(float f) {
  uint32_t u = __builtin_bit_cast(uint32_t, f);
  u += 0x7fffu + ((u >> 16) & 1u);
  return (u16)(u >> 16);
}
__device__ __forceinline__ float bf2f(u16 v) {
  uint32_t x = (uint32_t)v << 16;
  return __builtin_bit_cast(float, x);
}

// 16-lane-row reductions in the VALU pipe via DPP.
__device__ __forceinline__ float row16_max(float v) {
  int t;
  t = __builtin_amdgcn_update_dpp(0, __builtin_bit_cast(int, v), 0xB1, 0xF, 0xF, true);
  v = fmaxf(v, __builtin_bit_cast(float, t));
  t = __builtin_amdgcn_update_dpp(0, __builtin_bit_cast(int, v), 0x4E, 0xF, 0xF, true);
  v = fmaxf(v, __builtin_bit_cast(float, t));
  t = __builtin_amdgcn_update_dpp(0, __builtin_bit_cast(int, v), 0x124, 0xF, 0xF, true);
  v = fmaxf(v, __builtin_bit_cast(float, t));
  t = __builtin_amdgcn_update_dpp(0, __builtin_bit_cast(int, v), 0x128, 0xF, 0xF, true);
  v = fmaxf(v, __builtin_bit_cast(float, t));
  return v;
}
__device__ __forceinline__ float row16_sum(float v) {
  int t;
  t = __builtin_amdgcn_update_dpp(0, __builtin_bit_cast(int, v), 0xB1, 0xF, 0xF, true);
  v += __builtin_bit_cast(float, t);
  t = __builtin_amdgcn_update_dpp(0, __builtin_bit_cast(int, v), 0x4E, 0xF, 0xF, true);
  v += __builtin_bit_cast(float, t);
  t = __builtin_amdgcn_update_dpp(0, __builtin_bit_cast(int, v), 0x124, 0xF, 0xF, true);
  v += __builtin_bit_cast(float, t);
  t = __builtin_amdgcn_update_dpp(0, __builtin_bit_cast(int, v), 0x128, 0xF, 0xF, true);
  v += __builtin_bit_cast(float, t);
  return v;
}

// ---------------- cast x (f32 -> bf16), 8 elems/thread ----------------
__global__ void cvt_kernel(const float* __restrict__ in, u16* __restrict__ out) {
  int i = blockIdx.x * 256 + threadIdx.x;
  const float4* p = (const float4*)in + (size_t)i * 2;
  float4 a = p[0], b = p[1];
  u16x8 o;
  o[0] = f2bf(a.x); o[1] = f2bf(a.y); o[2] = f2bf(a.z); o[3] = f2bf(a.w);
  o[4] = f2bf(b.x); o[5] = f2bf(b.y); o[6] = f2bf(b.z); o[7] = f2bf(b.w);
  *((u16x8*)out + i) = o;
}

// ------------- transpose f32 [bz][R][C] -> bf16 [bz][C][R] -------------
__global__ void transpose_f2b(const float* __restrict__ in, u16* __restrict__ out,
                              int R, int C) {
  __shared__ float tile[32][33];
  const int bz = blockIdx.z;
  in  += (size_t)bz * R * C;
  out += (size_t)bz * R * C;
  int c0 = blockIdx.x * 32, r0 = blockIdx.y * 32;
  int tx = threadIdx.x, ty = threadIdx.y;
  #pragma unroll
  for (int i = 0; i < 32; i += 8)
    tile[ty + i][tx] = in[(size_t)(r0 + ty + i) * C + c0 + tx];
  __syncthreads();
  #pragma unroll
  for (int i = 0; i < 32; i += 8)
    out[(size_t)(c0 + ty + i) * R + r0 + tx] = f2bf(tile[tx][ty + i]);
}

// ------------- transpose bf16 [bz][R][C] -> bf16 [bz][C][R] ------------
__global__ void transpose_b2b(const u16* __restrict__ in, u16* __restrict__ out,
                              int R, int C) {
  __shared__ u16 tile[32][33];
  const int bz = blockIdx.z;
  in  += (size_t)bz * R * C;
  out += (size_t)bz * R * C;
  int c0 = blockIdx.x * 32, r0 = blockIdx.y * 32;
  int tx = threadIdx.x, ty = threadIdx.y;
  #pragma unroll
  for (int i = 0; i < 32; i += 8)
    tile[ty + i][tx] = in[(size_t)(r0 + ty + i) * C + c0 + tx];
  __syncthreads();
  #pragma unroll
  for (int i = 0; i < 32; i += 8)
    out[(size_t)(c0 + ty + i) * R + r0 + tx] = tile[tx][ty + i];
}

// ---------------- 128x128x64 bf16 MFMA GEMM (m97 structure) ----------------
template <int EPI>
__global__ __launch_bounds__(256) void gemm128(
    const u16* __restrict__ A, const u16* __restrict__ Bt, int K,
    const float* __restrict__ bias,
    u16* __restrict__ kb, u16* __restrict__ qb, u16* __restrict__ vb,
    float* __restrict__ fout) {
  __shared__ __align__(16) u16 As[128 * 64];
  __shared__ __align__(16) u16 Bs[128 * 64];
  const int tid = threadIdx.x;
  const int lane = tid & 63;
  const int wr = (tid >> 6) >> 1, wc = (tid >> 6) & 1;
  const int row0 = blockIdx.y * 128, col0 = blockIdx.x * 128;
  const int l15 = lane & 15, l4 = lane >> 4;
  const u16* Ablk = A + (size_t)row0 * K;
  const u16* Bblk = Bt + (size_t)col0 * K;
  f32x4 acc[4][4] = {};
  for (int k0 = 0; k0 < K; k0 += 64) {
    #pragma unroll
    for (int i = 0; i < 4; i++) {
      int off = (i * 256 + tid) * 8;
      int r = off >> 6, c = off & 63;
      GLD16(Ablk + (size_t)r * K + k0 + c, As + off);
    }
    #pragma unroll
    for (int i = 0; i < 4; i++) {
      int off = (i * 256 + tid) * 8;
      int r = off >> 6, c = off & 63;
      GLD16(Bblk + (size_t)r * K + k0 + c, Bs + off);
    }
    __syncthreads();
    #pragma unroll
    for (int kc = 0; kc < 2; kc++) {
      s16x8 af[4], bfr[4];
      #pragma unroll
      for (int m = 0; m < 4; m++)
        af[m] = *(const s16x8*)(As + (wr * 64 + m * 16 + l15) * 64 + kc * 32 + l4 * 8);
      #pragma unroll
      for (int n = 0; n < 4; n++)
        bfr[n] = *(const s16x8*)(Bs + (wc * 64 + n * 16 + l15) * 64 + kc * 32 + l4 * 8);
      #pragma unroll
      for (int m = 0; m < 4; m++)
        #pragma unroll
        for (int n = 0; n < 4; n++)
          acc[m][n] = __builtin_amdgcn_mfma_f32_16x16x32_bf16(af[m], bfr[n], acc[m][n], 0, 0, 0);
    }
    __syncthreads();
  }
  const int rbase = row0 + wr * 64;
  const int cbase = col0 + wc * 64;
  if (EPI == 0) {
    #pragma unroll
    for (int n = 0; n < 4; n++) {
      int c = cbase + n * 16 + l15;
      int h = c / 192, rr = c % 192;
      int part = rr >> 6, d = rr & 63;
      float bv = bias[h * 192 + rr];
      u16* dst = (part == 0) ? kb : (part == 1) ? qb : vb;
      float sc = (part == 1) ? 0.125f * 1.44269504f : 1.0f;  // 1/sqrt(hd) * log2e
      #pragma unroll
      for (int m = 0; m < 4; m++)
        #pragma unroll
        for (int i = 0; i < 4; i++) {
          int r = rbase + m * 16 + l4 * 4 + i;
          int b = r >> 11, nn = r & 2047;
          dst[(((size_t)(b * 16 + h) * 2048 + nn) << 6) + d] = f2bf((acc[m][n][i] + bv) * sc);
        }
    }
  } else {
    #pragma unroll
    for (int n = 0; n < 4; n++) {
      int c = cbase + n * 16 + l15;
      float bv = bias[c];
      #pragma unroll
      for (int m = 0; m < 4; m++)
        #pragma unroll
        for (int i = 0; i < 4; i++) {
          int r = rbase + m * 16 + l4 * 4 + i;
          fout[(size_t)r * 1024 + c] = acc[m][n][i] + bv;
        }
    }
  }
}

// ---------------- causal flash attention (v5) ----------------
// 960 work units (q-tile x KV-chunk, <=12 kt-iters each) via descending-size
// work stealing; grid 768 = 3 blocks/CU. Split tiles (qt>=6) write normalized
// bf16 partials + (m,l); merge_kernel combines 2-3 chunks. T13 defer-rescale,
// T5 setprio, dbuf LDS + counted vmcnt, DPP softmax reductions.
// unit type table: entry = qt*4 + c (c==3 -> full tile), descending iter count
__device__ const unsigned char UNIT_TAB[30] = {
  23, 44, 45, 40, 41, 61, 62, 19, 36, 37, 54, 56, 57, 58, 60,
  32, 33, 49, 50, 52, 53, 15, 28, 29, 48, 24, 25, 11, 7, 3};

__device__ __forceinline__ int toff_of(int qt) {
  return (qt <= 11) ? (qt - 6) * 2 : 12 + (qt - 12) * 3;
}

__global__ __launch_bounds__(256, 3) void attn_kernel(
    const u16* __restrict__ q, const u16* __restrict__ k,
    const u16* __restrict__ vt, u16* __restrict__ sa,
    u16* __restrict__ po, float* __restrict__ pm, float* __restrict__ pl,
    uint32_t* __restrict__ ctr) {
  __shared__ __align__(16) u16 Ks[2][64 * 64];
  __shared__ __align__(16) u16 Vs[2][64 * 64];
  __shared__ __align__(16) u16 Ps[4][2][16][72];
  __shared__ uint32_t s_unit;
  const int tid = threadIdx.x;
  const int lane = tid & 63;
  const int wave = tid >> 6;
  const int l15 = lane & 15, l4 = lane >> 4;

  for (;;) {
    if (tid == 0) s_unit = atomicAdd(ctr, 1u);
    __syncthreads();
    uint32_t u = s_unit;
    if (u >= 960u) break;
    const int bh = (int)(u & 31u);
    const int ty = (int)UNIT_TAB[u >> 5];
    const int qt = ty >> 2, cc = ty & 3;
    int kt0, kt1;
    if (cc == 3) { kt0 = 0; kt1 = 2 * qt + 1; }
    else {
      int n = 2 * qt + 2, nc = (qt <= 11) ? 2 : 3;
      kt0 = (cc * n) / nc;
      kt1 = ((cc + 1) * n) / nc - 1;
    }
    const int wr0 = qt * 128 + wave * 32;

    const u16* kbh = k + (((size_t)bh * 2048) << 6);
    const u16* vbh = vt + (size_t)bh * 64 * 2048;

    // prologue stage of kt0 into buffer 0
    #pragma unroll
    for (int i = 0; i < 2; i++) {
      int off = (i * 256 + tid) * 16;
      int row = off >> 7;
      int cs = (off & 127) ^ ((row & 7) << 4);
      GLD16(kbh + (((size_t)(kt0 * 64 + row)) << 6) + (cs >> 1), &Ks[0][0] + (off >> 1));
      GLD16(vbh + (size_t)row * 2048 + kt0 * 64 + (cs >> 1), &Vs[0][0] + (off >> 1));
    }

    // Q fragments (A-frag: row=l15, k=kc*32+l4*8+j)
    s16x8 qf[2][2];
    #pragma unroll
    for (int f = 0; f < 2; f++) {
      const u16* qrow = q + (((size_t)bh * 2048 + wr0 + f * 16 + l15) << 6);
      qf[f][0] = *(const s16x8*)(qrow + l4 * 8);
      qf[f][1] = *(const s16x8*)(qrow + 32 + l4 * 8);
    }

    f32x4 o[2][4] = {};
    float m_[2][4], l_[2][4];
    #pragma unroll
    for (int f = 0; f < 2; f++)
      #pragma unroll
      for (int r = 0; r < 4; r++) { m_[f][r] = -3e38f; l_[f][r] = 0.f; }

    int cur = 0;
    for (int kt = kt0; kt <= kt1; kt++) {
      if (kt < kt1) {
        u16* KsB = &Ks[cur ^ 1][0];
        u16* VsB = &Vs[cur ^ 1][0];
        #pragma unroll
        for (int i = 0; i < 2; i++) {
          int off = (i * 256 + tid) * 16;
          int row = off >> 7;
          int cs = (off & 127) ^ ((row & 7) << 4);
          GLD16(kbh + (((size_t)((kt + 1) * 64 + row)) << 6) + (cs >> 1), KsB + (off >> 1));
          GLD16(vbh + (size_t)row * 2048 + (kt + 1) * 64 + (cs >> 1), VsB + (off >> 1));
        }
        asm volatile("s_waitcnt vmcnt(4)" ::: "memory");
      } else {
        asm volatile("s_waitcnt vmcnt(0)" ::: "memory");
      }
      __builtin_amdgcn_s_barrier();
      __builtin_amdgcn_sched_barrier(0);

      const bool live0 = (kt * 64) <= (wr0 + 15);
      const bool live1 = (kt * 64) <= (wr0 + 31);
      if (live0 | live1) {
        const char* Kc = (const char*)&Ks[cur][0];
        const char* Vc = (const char*)&Vs[cur][0];
        const int sw = (l15 & 7) << 4;
        f32x4 s[2][4] = {};
        __builtin_amdgcn_s_setprio(1);
        #pragma unroll
        for (int t = 0; t < 4; t++) {
          int rowb = (t * 16 + l15) << 7;
          s16x8 kf0 = *(const s16x8*)(Kc + rowb + ((l4 * 16) ^ sw));
          s16x8 kf1 = *(const s16x8*)(Kc + rowb + ((64 + l4 * 16) ^ sw));
          if (live0) {
            s[0][t] = __builtin_amdgcn_mfma_f32_16x16x32_bf16(qf[0][0], kf0, s[0][t], 0, 0, 0);
            s[0][t] = __builtin_amdgcn_mfma_f32_16x16x32_bf16(qf[0][1], kf1, s[0][t], 0, 0, 0);
          }
          if (live1) {
            s[1][t] = __builtin_amdgcn_mfma_f32_16x16x32_bf16(qf[1][0], kf0, s[1][t], 0, 0, 0);
            s[1][t] = __builtin_amdgcn_mfma_f32_16x16x32_bf16(qf[1][1], kf1, s[1][t], 0, 0, 0);
          }
        }
        __builtin_amdgcn_s_setprio(0);
        // causal mask (only near-diagonal tiles trigger)
        #pragma unroll
        for (int f = 0; f < 2; f++) {
          if (!(f ? live1 : live0)) continue;
          const int wr0f = wr0 + f * 16;
          if (kt * 64 + 63 > wr0f) {
            #pragma unroll
            for (int t = 0; t < 4; t++)
              #pragma unroll
              for (int i = 0; i < 4; i++)
                if (kt * 64 + t * 16 + l15 > wr0f + l4 * 4 + i) s[f][t][i] = -3e38f;
          }
        }
        // online softmax with T13 defer-rescale (exp2 domain)
        float sm[2][4];
        bool need = false;
        #pragma unroll
        for (int f = 0; f < 2; f++) {
          if (!(f ? live1 : live0)) continue;
          #pragma unroll
          for (int r = 0; r < 4; r++) {
            float v = fmaxf(fmaxf(s[f][0][r], s[f][1][r]), fmaxf(s[f][2][r], s[f][3][r]));
            v = row16_max(v);
            sm[f][r] = v;
            need |= (v > m_[f][r] + 11.f);
          }
        }
        if (__any((int)need)) {
          #pragma unroll
          for (int f = 0; f < 2; f++) {
            if (!(f ? live1 : live0)) continue;
            #pragma unroll
            for (int r = 0; r < 4; r++) {
              float mn = fmaxf(m_[f][r], sm[f][r]);
              float al = exp2f(m_[f][r] - mn);
              m_[f][r] = mn;
              float rs = 0.f;
              #pragma unroll
              for (int t = 0; t < 4; t++) {
                float pv = exp2f(s[f][t][r] - mn);
                s[f][t][r] = pv;
                rs += pv;
              }
              rs = row16_sum(rs);
              l_[f][r] = l_[f][r] * al + rs;
              #pragma unroll
              for (int t = 0; t < 4; t++) o[f][t][r] *= al;
            }
          }
        } else {
          #pragma unroll
          for (int f = 0; f < 2; f++) {
            if (!(f ? live1 : live0)) continue;
            #pragma unroll
            for (int r = 0; r < 4; r++) {
              float mn = m_[f][r];
              float rs = 0.f;
              #pragma unroll
              for (int t = 0; t < 4; t++) {
                float pv = exp2f(s[f][t][r] - mn);
                s[f][t][r] = pv;
                rs += pv;
              }
              rs = row16_sum(rs);
              l_[f][r] += rs;
            }
          }
        }
        // P (D-layout) -> per-wave LDS -> A-frag
        #pragma unroll
        for (int f = 0; f < 2; f++) {
          if (!(f ? live1 : live0)) continue;
          #pragma unroll
          for (int t = 0; t < 4; t++)
            #pragma unroll
            for (int r = 0; r < 4; r++)
              Ps[wave][f][l4 * 4 + r][t * 16 + l15] = f2bf(s[f][t][r]);
        }
        s16x8 pa[2][2];
        #pragma unroll
        for (int f = 0; f < 2; f++) {
          if (!(f ? live1 : live0)) continue;
          pa[f][0] = *(const s16x8*)&Ps[wave][f][l15][l4 * 8];
          pa[f][1] = *(const s16x8*)&Ps[wave][f][l15][32 + l4 * 8];
        }
        __builtin_amdgcn_s_setprio(1);
        #pragma unroll
        for (int t = 0; t < 4; t++) {
          int rowb = (t * 16 + l15) << 7;
          s16x8 vf0 = *(const s16x8*)(Vc + rowb + ((l4 * 16) ^ sw));
          s16x8 vf1 = *(const s16x8*)(Vc + rowb + ((64 + l4 * 16) ^ sw));
          if (live0) {
            o[0][t] = __builtin_amdgcn_mfma_f32_16x16x32_bf16(pa[0][0], vf0, o[0][t], 0, 0, 0);
            o[0][t] = __builtin_amdgcn_mfma_f32_16x16x32_bf16(pa[0][1], vf1, o[0][t], 0, 0, 0);
          }
          if (live1) {
            o[1][t] = __builtin_amdgcn_mfma_f32_16x16x32_bf16(pa[1][0], vf0, o[1][t], 0, 0, 0);
            o[1][t] = __builtin_amdgcn_mfma_f32_16x16x32_bf16(pa[1][1], vf1, o[1][t], 0, 0, 0);
          }
        }
        __builtin_amdgcn_s_setprio(0);
      }
      asm volatile("" ::: "memory");
      __builtin_amdgcn_sched_barrier(0);
      __builtin_amdgcn_s_barrier();
      cur ^= 1;
    }
    // epilogue
    if (cc == 3) {
      const int b = bh >> 4, h = bh & 15;
      #pragma unroll
      for (int f = 0; f < 2; f++)
        #pragma unroll
        for (int r = 0; r < 4; r++) {
          float inv = 1.f / l_[f][r];
          int n = wr0 + f * 16 + l4 * 4 + r;
          u16* dst = sa + ((size_t)(b * 2048 + n) << 10) + h * 64;
          #pragma unroll
          for (int t = 0; t < 4; t++)
            dst[t * 16 + l15] = f2bf(o[f][t][r] * inv);
        }
    } else {
      const int pid = bh * 24 + toff_of(qt) + cc;
      #pragma unroll
      for (int f = 0; f < 2; f++)
        #pragma unroll
        for (int r = 0; r < 4; r++) {
          float inv = 1.f / l_[f][r];
          int row = wave * 32 + f * 16 + l4 * 4 + r;
          u16* dst = po + ((size_t)pid * 128 + row) * 64;
          #pragma unroll
          for (int t = 0; t < 4; t++)
            dst[t * 16 + l15] = f2bf(o[f][t][r] * inv);
          if (l15 == 0) {
            pm[(size_t)pid * 128 + row] = m_[f][r];
            pl[(size_t)pid * 128 + row] = l_[f][r];
          }
        }
    }
  }
}

// ---------------- merge partial chunks (2 or 3) per (bh, qt>=6) ----------------
__global__ __launch_bounds__(256) void merge_kernel(
    const u16* __restrict__ po, const float* __restrict__ pm,
    const float* __restrict__ pl, u16* __restrict__ sa) {
  const int bid = blockIdx.x;       // 320 = 32 bh x 10 tiles
  const int bh = bid & 31, qt = 6 + (bid >> 5);
  const int nc = (qt <= 11) ? 2 : 3;
  const int base = bh * 24 + toff_of(qt);
  const int tid = threadIdx.x;
  const int row = tid >> 1, half = tid & 1;

  float m0 = pm[(size_t)(base + 0) * 128 + row];
  float m1 = pm[(size_t)(base + 1) * 128 + row];
  float l0 = pl[(size_t)(base + 0) * 128 + row];
  float l1 = pl[(size_t)(base + 1) * 128 + row];
  float m2 = -3e38f, l2 = 0.f;
  if (nc == 3) {
    m2 = pm[(size_t)(base + 2) * 128 + row];
    l2 = pl[(size_t)(base + 2) * 128 + row];
  }
  float m = fmaxf(fmaxf(m0, m1), m2);
  float w0 = exp2f(m0 - m) * l0;
  float w1 = exp2f(m1 - m) * l1;
  float w2 = (nc == 3) ? exp2f(m2 - m) * l2 : 0.f;
  float invW = 1.f / (w0 + w1 + w2);

  const int c0 = half * 32;
  float acc[32];
  {
    const u16* s0 = po + ((size_t)(base + 0) * 128 + row) * 64 + c0;
    #pragma unroll
    for (int v = 0; v < 4; v++) {
      u16x8 d = *(const u16x8*)(s0 + v * 8);
      #pragma unroll
      for (int j = 0; j < 8; j++) acc[v * 8 + j] = bf2f(d[j]) * w0;
    }
  }
  {
    const u16* s1 = po + ((size_t)(base + 1) * 128 + row) * 64 + c0;
    #pragma unroll
    for (int v = 0; v < 4; v++) {
      u16x8 d = *(const u16x8*)(s1 + v * 8);
      #pragma unroll
      for (int j = 0; j < 8; j++) acc[v * 8 + j] += bf2f(d[j]) * w1;
    }
  }
  if (nc == 3) {
    const u16* s2 = po + ((size_t)(base + 2) * 128 + row) * 64 + c0;
    #pragma unroll
    for (int v = 0; v < 4; v++) {
      u16x8 d = *(const u16x8*)(s2 + v * 8);
      #pragma unroll
      for (int j = 0; j < 8; j++) acc[v * 8 + j] += bf2f(d[j]) * w2;
    }
  }
  const int b = bh >> 4, h = bh & 15;
  u16* dst = sa + ((size_t)(b * 2048 + qt * 128 + row) << 10) + h * 64 + c0;
  #pragma unroll
  for (int v = 0; v < 4; v++) {
    u16x8 d;
    #pragma unroll
    for (int j = 0; j < 8; j++) d[j] = f2bf(acc[v * 8 + j] * invW);
    *(u16x8*)(dst + v * 8) = d;
  }
}

extern "C" void kernel_launch(void* const* d_in, const int* in_sizes, int n_in,
                              void* d_out, int out_size, void* d_ws, size_t ws_size,
                              hipStream_t stream) {
  const float* x    = (const float*)d_in[0];
  const float* Wqkv = (const float*)d_in[1];
  const float* bqkv = (const float*)d_in[2];
  const float* Wo   = (const float*)d_in[3];
  const float* bo   = (const float*)d_in[4];
  float* out = (float*)d_out;

  // workspace carve (u16 elements)
  u16* xb  = (u16*)d_ws;          // [4096][1024] (reused as sab after qkv gemm)
  u16* wqt = xb + 4194304;        // [16*192][1024]
  u16* wot = wqt + 3145728;       // [1024][1024]
  u16* qb  = wot + 1048576;       // [32][2048][64]
  u16* kb  = qb + 4194304;
  u16* vtb = kb + 4194304;        // [32][64][2048]
  u16* vb  = vtb + 4194304;       // [32][2048][64] (dead after b2b; po overlays)
  u16* sab = xb;
  uint32_t* ctr = (uint32_t*)wqt; // wqt dead after qkv gemm
  u16* po = vb;                   // 768 partials x [128][64] bf16 = 12.6MB
  float* pm = (float*)(po + (size_t)768 * 128 * 64);
  float* pl = pm + 768 * 128;

  cvt_kernel<<<2048, 256, 0, stream>>>(x, xb);
  transpose_f2b<<<dim3(6, 32, 16), dim3(32, 8), 0, stream>>>(Wqkv, wqt, 1024, 192);
  transpose_f2b<<<dim3(32, 32, 1), dim3(32, 8), 0, stream>>>(Wo, wot, 1024, 1024);
  gemm128<0><<<dim3(24, 32), 256, 0, stream>>>(xb, wqt, 1024, bqkv, kb, qb, vb, nullptr);
  transpose_b2b<<<dim3(2, 64, 32), dim3(32, 8), 0, stream>>>(vb, vtb, 2048, 64);
  hipMemsetAsync(ctr, 0, sizeof(uint32_t), stream);
  attn_kernel<<<dim3(768), 256, 0, stream>>>(qb, kb, vtb, sab, po, pm, pl, ctr);
  merge_kernel<<<dim3(320), 256, 0, stream>>>(po, pm, pl, sab);
  gemm128<1><<<dim3(8, 32), 256, 0, stream>>>(sab, wot, 1024, bo, nullptr, nullptr, nullptr, out);
}

// Round 6
// 253.039 us; speedup vs baseline: 1.7149x; 1.7149x over previous
//
#include <hip/hip_runtime.h>
#include <stdint.h>

typedef unsigned short u16;
typedef short s16x8 __attribute__((ext_vector_type(8)));
typedef unsigned short u16x8 __attribute__((ext_vector_type(8)));
typedef unsigned int u32x4 __attribute__((ext_vector_type(4)));
typedef float f32x4 __attribute__((ext_vector_type(4)));
typedef float f32x16 __attribute__((ext_vector_type(16)));

#define GLD16(g, l) __builtin_amdgcn_global_load_lds( \
    (const __attribute__((address_space(1))) uint32_t*)(g), \
    (__attribute__((address_space(3))) uint32_t*)(l), 16, 0, 0)

__device__ __forceinline__ u16 f2bf(float f) {
  uint32_t u = __builtin_bit_cast(uint32_t, f);
  u += 0x7fffu + ((u >> 16) & 1u);
  return (u16)(u >> 16);
}

// packed f32x2 -> bf16x2 (RNE); no builtin on gfx950 (T12 recipe)
__device__ __forceinline__ uint32_t cvtpk(float lo, float hi) {
  uint32_t r;
  asm("v_cvt_pk_bf16_f32 %0, %1, %2" : "=v"(r) : "v"(lo), "v"(hi));
  return r;
}

// ---------------- cast x (f32 -> bf16), 8 elems/thread ----------------
__global__ void cvt_kernel(const float* __restrict__ in, u16* __restrict__ out) {
  int i = blockIdx.x * 256 + threadIdx.x;
  const float4* p = (const float4*)in + (size_t)i * 2;
  float4 a = p[0], b = p[1];
  u16x8 o;
  o[0] = f2bf(a.x); o[1] = f2bf(a.y); o[2] = f2bf(a.z); o[3] = f2bf(a.w);
  o[4] = f2bf(b.x); o[5] = f2bf(b.y); o[6] = f2bf(b.z); o[7] = f2bf(b.w);
  *((u16x8*)out + i) = o;
}

// ------------- transpose f32 [bz][R][C] -> bf16 [bz][C][R] -------------
__global__ void transpose_f2b(const float* __restrict__ in, u16* __restrict__ out,
                              int R, int C) {
  __shared__ float tile[32][33];
  const int bz = blockIdx.z;
  in  += (size_t)bz * R * C;
  out += (size_t)bz * R * C;
  int c0 = blockIdx.x * 32, r0 = blockIdx.y * 32;
  int tx = threadIdx.x, ty = threadIdx.y;
  #pragma unroll
  for (int i = 0; i < 32; i += 8)
    tile[ty + i][tx] = in[(size_t)(r0 + ty + i) * C + c0 + tx];
  __syncthreads();
  #pragma unroll
  for (int i = 0; i < 32; i += 8)
    out[(size_t)(c0 + ty + i) * R + r0 + tx] = f2bf(tile[tx][ty + i]);
}

// ------------- transpose bf16 [bz][R][C] -> bf16 [bz][C][R] ------------
__global__ void transpose_b2b(const u16* __restrict__ in, u16* __restrict__ out,
                              int R, int C) {
  __shared__ u16 tile[32][33];
  const int bz = blockIdx.z;
  in  += (size_t)bz * R * C;
  out += (size_t)bz * R * C;
  int c0 = blockIdx.x * 32, r0 = blockIdx.y * 32;
  int tx = threadIdx.x, ty = threadIdx.y;
  #pragma unroll
  for (int i = 0; i < 32; i += 8)
    tile[ty + i][tx] = in[(size_t)(r0 + ty + i) * C + c0 + tx];
  __syncthreads();
  #pragma unroll
  for (int i = 0; i < 32; i += 8)
    out[(size_t)(c0 + ty + i) * R + r0 + tx] = tile[tx][ty + i];
}

// ---------------- 128x128x64 bf16 MFMA GEMM (m97 structure) ----------------
template <int EPI>
__global__ __launch_bounds__(256) void gemm128(
    const u16* __restrict__ A, const u16* __restrict__ Bt, int K,
    const float* __restrict__ bias,
    u16* __restrict__ kb, u16* __restrict__ qb, u16* __restrict__ vb,
    float* __restrict__ fout) {
  __shared__ __align__(16) u16 As[128 * 64];
  __shared__ __align__(16) u16 Bs[128 * 64];
  const int tid = threadIdx.x;
  const int lane = tid & 63;
  const int wr = (tid >> 6) >> 1, wc = (tid >> 6) & 1;
  const int row0 = blockIdx.y * 128, col0 = blockIdx.x * 128;
  const int l15 = lane & 15, l4 = lane >> 4;
  const u16* Ablk = A + (size_t)row0 * K;
  const u16* Bblk = Bt + (size_t)col0 * K;
  f32x4 acc[4][4] = {};
  for (int k0 = 0; k0 < K; k0 += 64) {
    #pragma unroll
    for (int i = 0; i < 4; i++) {
      int off = (i * 256 + tid) * 8;
      int r = off >> 6, c = off & 63;
      GLD16(Ablk + (size_t)r * K + k0 + c, As + off);
    }
    #pragma unroll
    for (int i = 0; i < 4; i++) {
      int off = (i * 256 + tid) * 8;
      int r = off >> 6, c = off & 63;
      GLD16(Bblk + (size_t)r * K + k0 + c, Bs + off);
    }
    __syncthreads();
    #pragma unroll
    for (int kc = 0; kc < 2; kc++) {
      s16x8 af[4], bfr[4];
      #pragma unroll
      for (int m = 0; m < 4; m++)
        af[m] = *(const s16x8*)(As + (wr * 64 + m * 16 + l15) * 64 + kc * 32 + l4 * 8);
      #pragma unroll
      for (int n = 0; n < 4; n++)
        bfr[n] = *(const s16x8*)(Bs + (wc * 64 + n * 16 + l15) * 64 + kc * 32 + l4 * 8);
      #pragma unroll
      for (int m = 0; m < 4; m++)
        #pragma unroll
        for (int n = 0; n < 4; n++)
          acc[m][n] = __builtin_amdgcn_mfma_f32_16x16x32_bf16(af[m], bfr[n], acc[m][n], 0, 0, 0);
    }
    __syncthreads();
  }
  const int rbase = row0 + wr * 64;
  const int cbase = col0 + wc * 64;
  if (EPI == 0) {
    #pragma unroll
    for (int n = 0; n < 4; n++) {
      int c = cbase + n * 16 + l15;
      int h = c / 192, rr = c % 192;
      int part = rr >> 6, d = rr & 63;
      float bv = bias[h * 192 + rr];
      u16* dst = (part == 0) ? kb : (part == 1) ? qb : vb;
      float sc = (part == 1) ? 0.125f * 1.44269504f : 1.0f;  // 1/sqrt(hd) * log2e
      #pragma unroll
      for (int m = 0; m < 4; m++)
        #pragma unroll
        for (int i = 0; i < 4; i++) {
          int r = rbase + m * 16 + l4 * 4 + i;
          int b = r >> 11, nn = r & 2047;
          dst[(((size_t)(b * 16 + h) * 2048 + nn) << 6) + d] = f2bf((acc[m][n][i] + bv) * sc);
        }
    }
  } else {
    #pragma unroll
    for (int n = 0; n < 4; n++) {
      int c = cbase + n * 16 + l15;
      float bv = bias[c];
      #pragma unroll
      for (int m = 0; m < 4; m++)
        #pragma unroll
        for (int i = 0; i < 4; i++) {
          int r = rbase + m * 16 + l4 * 4 + i;
          fout[(size_t)r * 1024 + c] = acc[m][n][i] + bv;
        }
    }
  }
}

// ---------------- causal flash attention (v6: swapped-operand, in-reg softmax) ---
// 32x32x16 MFMA. S^T = mfma(K, Q^T): lane owns q-row = lane&31; its 32 P values
// live in 2 f32x16 accumulators (kv = (reg&3)+8*(reg>>2)+4*(lane>>5) + 32*b).
// Softmax fully in-register (fmax tree + one shfl_xor(32)). P -> bf16 B-frags via
// v_cvt_pk_bf16_f32 + 8 shfl_xor(32). PV: O^T = mfma(V^T, P^T). Per-lane softmax
// state = 2 scalars. LDS = K/V dbuf only (32KB, XOR-swizzled, rule-#21 staging).
// 2-wave blocks, 1024 units of 64 q-rows, grid 1024 (4 blocks/CU), T13 + T5.
__global__ __launch_bounds__(128, 2) void attn_kernel(
    const u16* __restrict__ q, const u16* __restrict__ k,
    const u16* __restrict__ vt, u16* __restrict__ sa,
    uint32_t* __restrict__ ctr) {
  __shared__ __align__(16) u16 Ks[2][64 * 64];
  __shared__ __align__(16) u16 Vs[2][64 * 64];
  __shared__ uint32_t s_unit;
  const int tid = threadIdx.x;        // 0..127
  const int lane = tid & 63;
  const int wave = tid >> 6;          // 0,1
  const int l31 = lane & 31;
  const int h = lane >> 5;            // lane-half

  for (;;) {
    if (tid == 0) s_unit = atomicAdd(ctr, 1u);
    __syncthreads();
    uint32_t u = s_unit;
    if (u >= 1024u) break;
    const int bh = (int)(u & 31u);
    const int t = 31 - (int)(u >> 5);    // descending size: iters = t+1
    const int ktmax = t;
    const int qrow = t * 64 + wave * 32 + l31;  // this lane's q row

    const u16* kbh = k + (((size_t)bh * 2048) << 6);
    const u16* vbh = vt + (size_t)bh * 64 * 2048;

    // prologue: stage tile kt=0 (linear LDS dest + inverse-swizzled global src)
    #pragma unroll
    for (int i = 0; i < 4; i++) {
      int off = (i * 128 + tid) * 16;   // byte in 8KB tile
      int row = off >> 7;
      int cs = (off & 127) ^ ((row & 7) << 4);
      GLD16(kbh + (((size_t)row) << 6) + (cs >> 1), (u16*)Ks[0] + (off >> 1));
      GLD16(vbh + (size_t)row * 2048 + (cs >> 1), (u16*)Vs[0] + (off >> 1));
    }

    // Q B-frags: col=lane&31 (q-row), k = c*16 + 8h + j
    const u16* qr = q + (((size_t)bh * 2048 + qrow) << 6);
    s16x8 qf[4];
    #pragma unroll
    for (int c = 0; c < 4; c++)
      qf[c] = *(const s16x8*)(qr + c * 16 + h * 8);

    f32x16 o0 = {}, o1 = {};
    float m_ = -3e38f, l_ = 0.f;

    int cur = 0;
    for (int kt = 0; kt <= ktmax; kt++) {
      if (kt < ktmax) {
        u16* KsB = (u16*)Ks[cur ^ 1];
        u16* VsB = (u16*)Vs[cur ^ 1];
        #pragma unroll
        for (int i = 0; i < 4; i++) {
          int off = (i * 128 + tid) * 16;
          int row = off >> 7;
          int cs = (off & 127) ^ ((row & 7) << 4);
          GLD16(kbh + (((size_t)((kt + 1) * 64 + row)) << 6) + (cs >> 1), KsB + (off >> 1));
          GLD16(vbh + (size_t)row * 2048 + (kt + 1) * 64 + (cs >> 1), VsB + (off >> 1));
        }
        asm volatile("s_waitcnt vmcnt(8)" ::: "memory");
      } else {
        asm volatile("s_waitcnt vmcnt(0)" ::: "memory");
      }
      __builtin_amdgcn_s_barrier();
      __builtin_amdgcn_sched_barrier(0);

      const char* Kc = (const char*)Ks[cur];
      const char* Vc = (const char*)Vs[cur];
      const int swz0 = ((l31 & 7) << 4);

      // S^T = K * Q^T  (A=K rows kv, B=Q^T cols q)
      f32x16 s0 = {}, s1 = {};
      __builtin_amdgcn_s_setprio(1);
      #pragma unroll
      for (int c = 0; c < 4; c++) {
        int cb = c * 32 + 16 * h;
        s16x8 kf0 = *(const s16x8*)(Kc + l31 * 128 + (cb ^ swz0));
        s16x8 kf1 = *(const s16x8*)(Kc + (32 + l31) * 128 + (cb ^ swz0));
        s0 = __builtin_amdgcn_mfma_f32_32x32x16_bf16(kf0, qf[c], s0, 0, 0, 0);
        s1 = __builtin_amdgcn_mfma_f32_32x32x16_bf16(kf1, qf[c], s1, 0, 0, 0);
      }
      __builtin_amdgcn_s_setprio(0);

      // causal mask (last tile only): kv = kt*64 + b*32 + (r&3)+8*(r>>2)+4h
      if (kt == ktmax) {
        int kvb = kt * 64 + 4 * h;
        #pragma unroll
        for (int r = 0; r < 16; r++) {
          int kv0 = kvb + (r & 3) + 8 * (r >> 2);
          s0[r] = (kv0 > qrow) ? -3e38f : s0[r];
          s1[r] = (kv0 + 32 > qrow) ? -3e38f : s1[r];
        }
      }

      // in-register online softmax (exp2 domain), T13 defer-rescale
      float pmax = -3e38f;
      #pragma unroll
      for (int r = 0; r < 16; r++)
        pmax = fmaxf(pmax, fmaxf(s0[r], s1[r]));
      pmax = fmaxf(pmax, __shfl_xor(pmax, 32));
      bool need = pmax > m_ + 11.f;
      if (__any((int)need)) {
        float mn = fmaxf(m_, pmax);
        float al = exp2f(m_ - mn);
        m_ = mn;
        l_ *= al;
        #pragma unroll
        for (int r = 0; r < 16; r++) { o0[r] *= al; o1[r] *= al; }
      }
      float rs = 0.f;
      #pragma unroll
      for (int r = 0; r < 16; r++) {
        float p0 = exp2f(s0[r] - m_);
        float p1 = exp2f(s1[r] - m_);
        s0[r] = p0; s1[r] = p1;
        rs += p0 + p1;
      }
      rs += __shfl_xor(rs, 32);
      l_ += rs;

      // pack P -> bf16 pairs: pk_b[g][t] = cvtpk(p[b][4g+2t], p[b][4g+2t+1])
      uint32_t pk0[4][2], pk1[4][2];
      #pragma unroll
      for (int g = 0; g < 4; g++) {
        pk0[g][0] = cvtpk(s0[4 * g + 0], s0[4 * g + 1]);
        pk0[g][1] = cvtpk(s0[4 * g + 2], s0[4 * g + 3]);
        pk1[g][0] = cvtpk(s1[4 * g + 0], s1[4 * g + 1]);
        pk1[g][1] = cvtpk(s1[4 * g + 2], s1[4 * g + 3]);
      }
      // build B-frags for PV step s=2b+sl via one half-swap exchange
      s16x8 pf[4];
      #pragma unroll
      for (int b = 0; b < 2; b++)
        #pragma unroll
        for (int sl = 0; sl < 2; sl++) {
          uint32_t a0, a1, sd0, sd1;
          if (b == 0) {
            a0 = h ? pk0[sl * 2 + 1][0] : pk0[sl * 2][0];
            a1 = h ? pk0[sl * 2 + 1][1] : pk0[sl * 2][1];
            sd0 = h ? pk0[sl * 2][0] : pk0[sl * 2 + 1][0];
            sd1 = h ? pk0[sl * 2][1] : pk0[sl * 2 + 1][1];
          } else {
            a0 = h ? pk1[sl * 2 + 1][0] : pk1[sl * 2][0];
            a1 = h ? pk1[sl * 2 + 1][1] : pk1[sl * 2][1];
            sd0 = h ? pk1[sl * 2][0] : pk1[sl * 2 + 1][0];
            sd1 = h ? pk1[sl * 2][1] : pk1[sl * 2 + 1][1];
          }
          uint32_t r0 = (uint32_t)__shfl_xor((int)sd0, 32);
          uint32_t r1 = (uint32_t)__shfl_xor((int)sd1, 32);
          u32x4 w;
          w[0] = h ? r0 : a0;
          w[1] = h ? r1 : a1;
          w[2] = h ? a0 : r0;
          w[3] = h ? a1 : r1;
          pf[b * 2 + sl] = __builtin_bit_cast(s16x8, w);
        }

      // O^T += V^T * P^T
      __builtin_amdgcn_s_setprio(1);
      #pragma unroll
      for (int ss = 0; ss < 4; ss++) {
        int cb = ss * 32 + 16 * h;
        s16x8 vf0 = *(const s16x8*)(Vc + l31 * 128 + (cb ^ swz0));
        s16x8 vf1 = *(const s16x8*)(Vc + (32 + l31) * 128 + (cb ^ swz0));
        o0 = __builtin_amdgcn_mfma_f32_32x32x16_bf16(vf0, pf[ss], o0, 0, 0, 0);
        o1 = __builtin_amdgcn_mfma_f32_32x32x16_bf16(vf1, pf[ss], o1, 0, 0, 0);
      }
      __builtin_amdgcn_s_setprio(0);

      __builtin_amdgcn_sched_barrier(0);
      __builtin_amdgcn_s_barrier();   // protect consumed buffer from restage
      cur ^= 1;
    }

    // epilogue: O^T col=lane&31 = q-row; d = (r&3)+8*(r>>2)+4h (+32 for o1)
    const float inv = 1.f / l_;
    const int b_ = bh >> 4, head = bh & 15;
    u16* dst = sa + ((size_t)(b_ * 2048 + qrow) << 10) + head * 64;
    #pragma unroll
    for (int i = 0; i < 8; i++) {
      int r = 2 * i;
      int d = (r & 3) + 8 * (r >> 2) + 4 * h;
      *(uint32_t*)(dst + d) = cvtpk(o0[r] * inv, o0[r + 1] * inv);
      *(uint32_t*)(dst + d + 32) = cvtpk(o1[r] * inv, o1[r + 1] * inv);
    }
  }
}

extern "C" void kernel_launch(void* const* d_in, const int* in_sizes, int n_in,
                              void* d_out, int out_size, void* d_ws, size_t ws_size,
                              hipStream_t stream) {
  const float* x    = (const float*)d_in[0];
  const float* Wqkv = (const float*)d_in[1];
  const float* bqkv = (const float*)d_in[2];
  const float* Wo   = (const float*)d_in[3];
  const float* bo   = (const float*)d_in[4];
  float* out = (float*)d_out;

  // workspace carve (u16 elements)
  u16* xb  = (u16*)d_ws;          // [4096][1024] (reused as sab after qkv gemm)
  u16* wqt = xb + 4194304;        // [16*192][1024]
  u16* wot = wqt + 3145728;       // [1024][1024]
  u16* qb  = wot + 1048576;       // [32][2048][64]
  u16* kb  = qb + 4194304;
  u16* vb  = kb + 4194304;        // [32][2048][64]
  u16* vtb = vb + 4194304;        // [32][64][2048]
  u16* sab = xb;                  // alias: x's bf16 copy dead after qkv gemm
  uint32_t* ctr = (uint32_t*)wqt; // alias: wqt dead after qkv gemm

  cvt_kernel<<<2048, 256, 0, stream>>>(x, xb);
  transpose_f2b<<<dim3(6, 32, 16), dim3(32, 8), 0, stream>>>(Wqkv, wqt, 1024, 192);
  transpose_f2b<<<dim3(32, 32, 1), dim3(32, 8), 0, stream>>>(Wo, wot, 1024, 1024);
  gemm128<0><<<dim3(24, 32), 256, 0, stream>>>(xb, wqt, 1024, bqkv, kb, qb, vb, nullptr);
  transpose_b2b<<<dim3(2, 64, 32), dim3(32, 8), 0, stream>>>(vb, vtb, 2048, 64);
  hipMemsetAsync(ctr, 0, sizeof(uint32_t), stream);
  attn_kernel<<<dim3(1024), 128, 0, stream>>>(qb, kb, vtb, sab, ctr);
  gemm128<1><<<dim3(8, 32), 256, 0, stream>>>(sab, wot, 1024, bo, nullptr, nullptr, nullptr, out);
}

// Round 7
// 214.781 us; speedup vs baseline: 2.0204x; 1.1781x over previous
//
#include <hip/hip_runtime.h>
#include <stdint.h>

typedef unsigned short u16;
typedef short s16x8 __attribute__((ext_vector_type(8)));
typedef unsigned short u16x8 __attribute__((ext_vector_type(8)));
typedef unsigned int u32x4 __attribute__((ext_vector_type(4)));
typedef float f32x4 __attribute__((ext_vector_type(4)));
typedef float f32x16 __attribute__((ext_vector_type(16)));

#define GLD16(g, l) __builtin_amdgcn_global_load_lds( \
    (const __attribute__((address_space(1))) uint32_t*)(g), \
    (__attribute__((address_space(3))) uint32_t*)(l), 16, 0, 0)

__device__ __forceinline__ u16 f2bf(float f) {
  uint32_t u = __builtin_bit_cast(uint32_t, f);
  u += 0x7fffu + ((u >> 16) & 1u);
  return (u16)(u >> 16);
}

// packed f32x2 -> bf16x2 (RNE); no builtin on gfx950 (T12 recipe)
__device__ __forceinline__ uint32_t cvtpk(float lo, float hi) {
  uint32_t r;
  asm("v_cvt_pk_bf16_f32 %0, %1, %2" : "=v"(r) : "v"(lo), "v"(hi));
  return r;
}

// ---------------- cast x (f32 -> bf16), 8 elems/thread ----------------
__global__ void cvt_kernel(const float* __restrict__ in, u16* __restrict__ out) {
  int i = blockIdx.x * 256 + threadIdx.x;
  const float4* p = (const float4*)in + (size_t)i * 2;
  float4 a = p[0], b = p[1];
  u16x8 o;
  o[0] = f2bf(a.x); o[1] = f2bf(a.y); o[2] = f2bf(a.z); o[3] = f2bf(a.w);
  o[4] = f2bf(b.x); o[5] = f2bf(b.y); o[6] = f2bf(b.z); o[7] = f2bf(b.w);
  *((u16x8*)out + i) = o;
}

// ------------- transpose f32 [bz][R][C] -> bf16 [bz][C][R] -------------
__global__ void transpose_f2b(const float* __restrict__ in, u16* __restrict__ out,
                              int R, int C) {
  __shared__ float tile[32][33];
  const int bz = blockIdx.z;
  in  += (size_t)bz * R * C;
  out += (size_t)bz * R * C;
  int c0 = blockIdx.x * 32, r0 = blockIdx.y * 32;
  int tx = threadIdx.x, ty = threadIdx.y;
  #pragma unroll
  for (int i = 0; i < 32; i += 8)
    tile[ty + i][tx] = in[(size_t)(r0 + ty + i) * C + c0 + tx];
  __syncthreads();
  #pragma unroll
  for (int i = 0; i < 32; i += 8)
    out[(size_t)(c0 + ty + i) * R + r0 + tx] = f2bf(tile[tx][ty + i]);
}

// ------------- transpose bf16 [bz][R][C] -> bf16 [bz][C][R] ------------
__global__ void transpose_b2b(const u16* __restrict__ in, u16* __restrict__ out,
                              int R, int C) {
  __shared__ u16 tile[32][33];
  const int bz = blockIdx.z;
  in  += (size_t)bz * R * C;
  out += (size_t)bz * R * C;
  int c0 = blockIdx.x * 32, r0 = blockIdx.y * 32;
  int tx = threadIdx.x, ty = threadIdx.y;
  #pragma unroll
  for (int i = 0; i < 32; i += 8)
    tile[ty + i][tx] = in[(size_t)(r0 + ty + i) * C + c0 + tx];
  __syncthreads();
  #pragma unroll
  for (int i = 0; i < 32; i += 8)
    out[(size_t)(c0 + ty + i) * R + r0 + tx] = tile[tx][ty + i];
}

// ---------------- 128x128x64 bf16 MFMA GEMM (m97 structure) ----------------
template <int EPI>
__global__ __launch_bounds__(256) void gemm128(
    const u16* __restrict__ A, const u16* __restrict__ Bt, int K,
    const float* __restrict__ bias,
    u16* __restrict__ kb, u16* __restrict__ qb, u16* __restrict__ vb,
    float* __restrict__ fout) {
  __shared__ __align__(16) u16 As[128 * 64];
  __shared__ __align__(16) u16 Bs[128 * 64];
  const int tid = threadIdx.x;
  const int lane = tid & 63;
  const int wr = (tid >> 6) >> 1, wc = (tid >> 6) & 1;
  const int row0 = blockIdx.y * 128, col0 = blockIdx.x * 128;
  const int l15 = lane & 15, l4 = lane >> 4;
  const u16* Ablk = A + (size_t)row0 * K;
  const u16* Bblk = Bt + (size_t)col0 * K;
  f32x4 acc[4][4] = {};
  for (int k0 = 0; k0 < K; k0 += 64) {
    #pragma unroll
    for (int i = 0; i < 4; i++) {
      int off = (i * 256 + tid) * 8;
      int r = off >> 6, c = off & 63;
      GLD16(Ablk + (size_t)r * K + k0 + c, As + off);
    }
    #pragma unroll
    for (int i = 0; i < 4; i++) {
      int off = (i * 256 + tid) * 8;
      int r = off >> 6, c = off & 63;
      GLD16(Bblk + (size_t)r * K + k0 + c, Bs + off);
    }
    __syncthreads();
    #pragma unroll
    for (int kc = 0; kc < 2; kc++) {
      s16x8 af[4], bfr[4];
      #pragma unroll
      for (int m = 0; m < 4; m++)
        af[m] = *(const s16x8*)(As + (wr * 64 + m * 16 + l15) * 64 + kc * 32 + l4 * 8);
      #pragma unroll
      for (int n = 0; n < 4; n++)
        bfr[n] = *(const s16x8*)(Bs + (wc * 64 + n * 16 + l15) * 64 + kc * 32 + l4 * 8);
      #pragma unroll
      for (int m = 0; m < 4; m++)
        #pragma unroll
        for (int n = 0; n < 4; n++)
          acc[m][n] = __builtin_amdgcn_mfma_f32_16x16x32_bf16(af[m], bfr[n], acc[m][n], 0, 0, 0);
    }
    __syncthreads();
  }
  const int rbase = row0 + wr * 64;
  const int cbase = col0 + wc * 64;
  if (EPI == 0) {
    #pragma unroll
    for (int n = 0; n < 4; n++) {
      int c = cbase + n * 16 + l15;
      int h = c / 192, rr = c % 192;
      int part = rr >> 6, d = rr & 63;
      float bv = bias[h * 192 + rr];
      u16* dst = (part == 0) ? kb : (part == 1) ? qb : vb;
      float sc = (part == 1) ? 0.125f * 1.44269504f : 1.0f;  // 1/sqrt(hd) * log2e
      #pragma unroll
      for (int m = 0; m < 4; m++)
        #pragma unroll
        for (int i = 0; i < 4; i++) {
          int r = rbase + m * 16 + l4 * 4 + i;
          int b = r >> 11, nn = r & 2047;
          dst[(((size_t)(b * 16 + h) * 2048 + nn) << 6) + d] = f2bf((acc[m][n][i] + bv) * sc);
        }
    }
  } else {
    #pragma unroll
    for (int n = 0; n < 4; n++) {
      int c = cbase + n * 16 + l15;
      float bv = bias[c];
      #pragma unroll
      for (int m = 0; m < 4; m++)
        #pragma unroll
        for (int i = 0; i < 4; i++) {
          int r = rbase + m * 16 + l4 * 4 + i;
          fout[(size_t)r * 1024 + c] = acc[m][n][i] + bv;
        }
    }
  }
}

// ---------------- causal flash attention (v7: static pairs + kv-split) ------
// 512 blocks x 4 waves. Block (bh, j) processes q-tiles (31-j) then (j)
// sequentially: exactly 33 kt-iters per block -> perfect static balance.
// Within a tile: wave = (p = row-half, q2 = kv-half); each wave computes a
// 32q x 32kv slice per iter (4 S-MFMA + 4 PV-MFMA, 32x32x16, swapped operands,
// in-register softmax on partial (m,l,O); kv-halves merged per tile via LDS).
// K/V dbuf LDS, XOR-swizzled (rule-#21 staging), counted vmcnt, T13, T5.
__global__ __launch_bounds__(256, 2) void attn_kernel(
    const u16* __restrict__ q, const u16* __restrict__ k,
    const u16* __restrict__ vt, u16* __restrict__ sa) {
  __shared__ __align__(16) u16 Ks[2][64 * 64];
  __shared__ __align__(16) u16 Vs[2][64 * 64];
  __shared__ __align__(16) float Mo[2][64][36];  // per-pair partner O (padded)
  __shared__ float Mml[2][64][2];
  const int tid = threadIdx.x;
  const int lane = tid & 63;
  const int wave = tid >> 6;      // 0..3
  const int p = wave & 1;         // row-half of the 64-row tile
  const int q2 = wave >> 1;       // kv-half of each 64-kv tile
  const int l31 = lane & 31;
  const int h = lane >> 5;

  const int bid = blockIdx.x;
  const int bh = (bid & 7) * 4 + ((bid >> 3) & 3);  // 4 bh per XCD (L2 locality)
  const int j = bid >> 5;                            // 0..15
  const u16* kbh = k + (((size_t)bh * 2048) << 6);
  const u16* vbh = vt + (size_t)bh * 64 * 2048;
  const int b_ = bh >> 4, head = bh & 15;
  const int swz = (l31 & 7) << 4;

  int cur = 0;
  for (int sub = 0; sub < 2; sub++) {
    const int t = sub ? j : (31 - j);
    const int qrow = t * 64 + p * 32 + l31;  // this lane's q row

    // prologue: stage kt=0 into buffer cur (linear dest, inv-swizzled src)
    #pragma unroll
    for (int i = 0; i < 2; i++) {
      int o2 = tid * 16 + i * 4096;
      int row = o2 >> 7;
      int cs = (o2 & 127) ^ ((row & 7) << 4);
      GLD16(kbh + (((size_t)row) << 6) + (cs >> 1), (u16*)Ks[cur] + (o2 >> 1));
      GLD16(vbh + (size_t)row * 2048 + (cs >> 1), (u16*)Vs[cur] + (o2 >> 1));
    }

    // Q B-frags: col = l31 (q-row), k-chunk c: d = c*16 + 8h + j
    const u16* qr = q + (((size_t)bh * 2048 + qrow) << 6);
    s16x8 qf[4];
    #pragma unroll
    for (int c = 0; c < 4; c++)
      qf[c] = *(const s16x8*)(qr + c * 16 + h * 8);

    f32x16 o0 = {}, o1 = {};
    float m_ = -3e38f, l_ = 0.f;

    for (int kt = 0; kt <= t; kt++) {
      if (kt < t) {
        u16* KsB = (u16*)Ks[cur ^ 1];
        u16* VsB = (u16*)Vs[cur ^ 1];
        #pragma unroll
        for (int i = 0; i < 2; i++) {
          int o2 = tid * 16 + i * 4096;
          int row = o2 >> 7;
          int cs = (o2 & 127) ^ ((row & 7) << 4);
          GLD16(kbh + (((size_t)((kt + 1) * 64 + row)) << 6) + (cs >> 1), KsB + (o2 >> 1));
          GLD16(vbh + (size_t)row * 2048 + (kt + 1) * 64 + (cs >> 1), VsB + (o2 >> 1));
        }
        asm volatile("s_waitcnt vmcnt(4)" ::: "memory");
      } else {
        asm volatile("s_waitcnt vmcnt(0)" ::: "memory");
      }
      __builtin_amdgcn_s_barrier();
      __builtin_amdgcn_sched_barrier(0);

      // wave fully masked only on diag tile, upper-kv x lower-row
      const bool active = !(kt == t && q2 == 1 && p == 0);
      if (active) {
        const char* Kc = (const char*)Ks[cur];
        const char* Vc = (const char*)Vs[cur];
        // S^T = K_half * Q^T : A rows kv = q2*32 + l31
        f32x16 s0 = {};
        __builtin_amdgcn_s_setprio(1);
        #pragma unroll
        for (int c = 0; c < 4; c++) {
          s16x8 kf = *(const s16x8*)(Kc + (q2 * 32 + l31) * 128 + ((c * 32 + 16 * h) ^ swz));
          s0 = __builtin_amdgcn_mfma_f32_32x32x16_bf16(kf, qf[c], s0, 0, 0, 0);
        }
        __builtin_amdgcn_s_setprio(0);

        // causal mask (diag tile only): kv = kt*64 + q2*32 + (r&3)+8*(r>>2)+4h
        if (kt == t) {
          int kvb = t * 64 + q2 * 32 + 4 * h;
          #pragma unroll
          for (int r = 0; r < 16; r++)
            if (kvb + (r & 3) + 8 * (r >> 2) > qrow) s0[r] = -3e38f;
        }

        // in-register online softmax (exp2 domain), T13 defer-rescale
        float pmax = s0[0];
        #pragma unroll
        for (int r = 1; r < 16; r++) pmax = fmaxf(pmax, s0[r]);
        pmax = fmaxf(pmax, __shfl_xor(pmax, 32));
        bool need = pmax > m_ + 11.f;
        if (__any((int)need)) {
          float mn = fmaxf(m_, pmax);
          float al = exp2f(m_ - mn);
          m_ = mn;
          l_ *= al;
          #pragma unroll
          for (int r = 0; r < 16; r++) { o0[r] *= al; o1[r] *= al; }
        }
        float rs = 0.f;
        #pragma unroll
        for (int r = 0; r < 16; r++) {
          float pv = exp2f(s0[r] - m_);
          s0[r] = pv;
          rs += pv;
        }
        rs += __shfl_xor(rs, 32);
        l_ += rs;

        // P -> bf16 B-frags (cvt_pk + half-swap exchange)
        uint32_t pk[8];
        #pragma unroll
        for (int g = 0; g < 8; g++)
          pk[g] = cvtpk(s0[2 * g], s0[2 * g + 1]);
        s16x8 pf[2];
        #pragma unroll
        for (int ss = 0; ss < 2; ss++) {
          uint32_t sendA = h ? pk[4 * ss + 0] : pk[4 * ss + 2];
          uint32_t sendB = h ? pk[4 * ss + 1] : pk[4 * ss + 3];
          uint32_t rA = (uint32_t)__shfl_xor((int)sendA, 32);
          uint32_t rB = (uint32_t)__shfl_xor((int)sendB, 32);
          u32x4 w;
          w[0] = h ? rA : pk[4 * ss + 0];
          w[1] = h ? rB : pk[4 * ss + 1];
          w[2] = h ? pk[4 * ss + 2] : rA;
          w[3] = h ? pk[4 * ss + 3] : rB;
          pf[ss] = __builtin_bit_cast(s16x8, w);
        }

        // O^T += V^T_half * P^T : A rows d = b2*32 + l31, k = kv chunk
        __builtin_amdgcn_s_setprio(1);
        #pragma unroll
        for (int ss = 0; ss < 2; ss++) {
          s16x8 vf0 = *(const s16x8*)(Vc + l31 * 128 + ((q2 * 64 + ss * 32 + 16 * h) ^ swz));
          s16x8 vf1 = *(const s16x8*)(Vc + (32 + l31) * 128 + ((q2 * 64 + ss * 32 + 16 * h) ^ swz));
          o0 = __builtin_amdgcn_mfma_f32_32x32x16_bf16(vf0, pf[ss], o0, 0, 0, 0);
          o1 = __builtin_amdgcn_mfma_f32_32x32x16_bf16(vf1, pf[ss], o1, 0, 0, 0);
        }
        __builtin_amdgcn_s_setprio(0);
      }
      __builtin_amdgcn_sched_barrier(0);
      __builtin_amdgcn_s_barrier();  // protect consumed buffer from restage
      cur ^= 1;
    }

    // ----- merge kv-halves (waves q2=1 -> LDS; waves q2=0 combine + store) ----
    if (q2) {
      float4* dst = (float4*)&Mo[p][lane][0];
      #pragma unroll
      for (int c = 0; c < 4; c++) {
        f32x4 a = {o0[4 * c], o0[4 * c + 1], o0[4 * c + 2], o0[4 * c + 3]};
        f32x4 b = {o1[4 * c], o1[4 * c + 1], o1[4 * c + 2], o1[4 * c + 3]};
        dst[c] = __builtin_bit_cast(float4, a);
        dst[4 + c] = __builtin_bit_cast(float4, b);
      }
      Mml[p][lane][0] = m_;
      Mml[p][lane][1] = l_;
    }
    __syncthreads();
    if (!q2) {
      float mB = Mml[p][lane][0], lB = Mml[p][lane][1];
      float ob[32];
      #pragma unroll
      for (int c = 0; c < 8; c++) {
        float4 v = ((const float4*)&Mo[p][lane][0])[c];
        ob[4 * c] = v.x; ob[4 * c + 1] = v.y; ob[4 * c + 2] = v.z; ob[4 * c + 3] = v.w;
      }
      float mS = fmaxf(m_, mB);
      float aA = exp2f(m_ - mS), aB = exp2f(mB - mS);
      float inv = 1.f / (l_ * aA + lB * aB);
      u16* dst = sa + ((size_t)(b_ * 2048 + qrow) << 10) + head * 64;
      #pragma unroll
      for (int i = 0; i < 8; i++) {
        int r = 2 * i;
        int d = (r & 3) + 8 * (r >> 2) + 4 * h;
        float v0 = (o0[r] * aA + ob[r] * aB) * inv;
        float v1 = (o0[r + 1] * aA + ob[r + 1] * aB) * inv;
        *(uint32_t*)(dst + d) = cvtpk(v0, v1);
        float w0 = (o1[r] * aA + ob[16 + r] * aB) * inv;
        float w1 = (o1[r + 1] * aA + ob[16 + r + 1] * aB) * inv;
        *(uint32_t*)(dst + d + 32) = cvtpk(w0, w1);
      }
    }
    __syncthreads();  // merge region reusable; stores drain (vmcnt) here too
  }
}

extern "C" void kernel_launch(void* const* d_in, const int* in_sizes, int n_in,
                              void* d_out, int out_size, void* d_ws, size_t ws_size,
                              hipStream_t stream) {
  const float* x    = (const float*)d_in[0];
  const float* Wqkv = (const float*)d_in[1];
  const float* bqkv = (const float*)d_in[2];
  const float* Wo   = (const float*)d_in[3];
  const float* bo   = (const float*)d_in[4];
  float* out = (float*)d_out;

  // workspace carve (u16 elements)
  u16* xb  = (u16*)d_ws;          // [4096][1024] (reused as sab after qkv gemm)
  u16* wqt = xb + 4194304;        // [16*192][1024]
  u16* wot = wqt + 3145728;       // [1024][1024]
  u16* qb  = wot + 1048576;       // [32][2048][64]
  u16* kb  = qb + 4194304;
  u16* vb  = kb + 4194304;        // [32][2048][64]
  u16* vtb = vb + 4194304;        // [32][64][2048]
  u16* sab = xb;                  // alias: x's bf16 copy dead after qkv gemm

  cvt_kernel<<<2048, 256, 0, stream>>>(x, xb);
  transpose_f2b<<<dim3(6, 32, 16), dim3(32, 8), 0, stream>>>(Wqkv, wqt, 1024, 192);
  transpose_f2b<<<dim3(32, 32, 1), dim3(32, 8), 0, stream>>>(Wo, wot, 1024, 1024);
  gemm128<0><<<dim3(24, 32), 256, 0, stream>>>(xb, wqt, 1024, bqkv, kb, qb, vb, nullptr);
  transpose_b2b<<<dim3(2, 64, 32), dim3(32, 8), 0, stream>>>(vb, vtb, 2048, 64);
  attn_kernel<<<dim3(512), 256, 0, stream>>>(qb, kb, vtb, sab);
  gemm128<1><<<dim3(8, 32), 256, 0, stream>>>(sab, wot, 1024, bo, nullptr, nullptr, nullptr, out);
}

// Round 8
// 195.787 us; speedup vs baseline: 2.2164x; 1.0970x over previous
//
#include <hip/hip_runtime.h>
#include <stdint.h>

typedef unsigned short u16;
typedef short s16x8 __attribute__((ext_vector_type(8)));
typedef unsigned short u16x8 __attribute__((ext_vector_type(8)));
typedef unsigned int u32x2 __attribute__((ext_vector_type(2)));
typedef unsigned int u32x4 __attribute__((ext_vector_type(4)));
typedef float f32x4 __attribute__((ext_vector_type(4)));
typedef float f32x16 __attribute__((ext_vector_type(16)));

#define GLD16(g, l) __builtin_amdgcn_global_load_lds( \
    (const __attribute__((address_space(1))) uint32_t*)(g), \
    (__attribute__((address_space(3))) uint32_t*)(l), 16, 0, 0)

__device__ __forceinline__ u16 f2bf(float f) {
  uint32_t u = __builtin_bit_cast(uint32_t, f);
  u += 0x7fffu + ((u >> 16) & 1u);
  return (u16)(u >> 16);
}

// packed f32x2 -> bf16x2 (RNE); no builtin on gfx950 (T12 recipe)
__device__ __forceinline__ uint32_t cvtpk(float lo, float hi) {
  uint32_t r;
  asm("v_cvt_pk_bf16_f32 %0, %1, %2" : "=v"(r) : "v"(lo), "v"(hi));
  return r;
}

// ---------------- cast x (f32 -> bf16), 8 elems/thread ----------------
__global__ void cvt_kernel(const float* __restrict__ in, u16* __restrict__ out) {
  int i = blockIdx.x * 256 + threadIdx.x;
  const float4* p = (const float4*)in + (size_t)i * 2;
  float4 a = p[0], b = p[1];
  u16x8 o;
  o[0] = f2bf(a.x); o[1] = f2bf(a.y); o[2] = f2bf(a.z); o[3] = f2bf(a.w);
  o[4] = f2bf(b.x); o[5] = f2bf(b.y); o[6] = f2bf(b.z); o[7] = f2bf(b.w);
  *((u16x8*)out + i) = o;
}

// ------------- transpose f32 [bz][R][C] -> bf16 [bz][C][R] -------------
__global__ void transpose_f2b(const float* __restrict__ in, u16* __restrict__ out,
                              int R, int C) {
  __shared__ float tile[32][33];
  const int bz = blockIdx.z;
  in  += (size_t)bz * R * C;
  out += (size_t)bz * R * C;
  int c0 = blockIdx.x * 32, r0 = blockIdx.y * 32;
  int tx = threadIdx.x, ty = threadIdx.y;
  #pragma unroll
  for (int i = 0; i < 32; i += 8)
    tile[ty + i][tx] = in[(size_t)(r0 + ty + i) * C + c0 + tx];
  __syncthreads();
  #pragma unroll
  for (int i = 0; i < 32; i += 8)
    out[(size_t)(c0 + ty + i) * R + r0 + tx] = f2bf(tile[tx][ty + i]);
}

// ------------- transpose bf16 [bz][R][C] -> bf16 [bz][C][R] ------------
__global__ void transpose_b2b(const u16* __restrict__ in, u16* __restrict__ out,
                              int R, int C) {
  __shared__ u16 tile[32][33];
  const int bz = blockIdx.z;
  in  += (size_t)bz * R * C;
  out += (size_t)bz * R * C;
  int c0 = blockIdx.x * 32, r0 = blockIdx.y * 32;
  int tx = threadIdx.x, ty = threadIdx.y;
  #pragma unroll
  for (int i = 0; i < 32; i += 8)
    tile[ty + i][tx] = in[(size_t)(r0 + ty + i) * C + c0 + tx];
  __syncthreads();
  #pragma unroll
  for (int i = 0; i < 32; i += 8)
    out[(size_t)(c0 + ty + i) * R + r0 + tx] = tile[tx][ty + i];
}

// ---------------- QKV GEMM v2: 128x128x64, T2 swizzle, swapped operands -----
// A = xb [4096][1024], Bt = wqt [3072][1024]. Swapped MFMA: C col(lane&15) =
// x-row, C reg axis = output column -> 4 consecutive d per lane -> cvtpk + 8B
// stores. Epilogue maps col -> (head, k/q/v, d); q scaled by 0.125*log2e.
__global__ __launch_bounds__(256) void gemm_qkv(
    const u16* __restrict__ A, const u16* __restrict__ Bt,
    const float* __restrict__ bias,
    u16* __restrict__ kb, u16* __restrict__ qb, u16* __restrict__ vb) {
  __shared__ __align__(16) u16 As[128 * 64];
  __shared__ __align__(16) u16 Bs[128 * 64];
  const int tid = threadIdx.x;
  const int lane = tid & 63;
  const int wr = (tid >> 6) >> 1, wc = (tid >> 6) & 1;
  const int l15 = lane & 15, l4 = lane >> 4;
  // bijective XCD swizzle: 768 = 8 * 96; row-chunks share A-panels in L2
  const int lin = blockIdx.x;
  const int wg = (lin & 7) * 96 + (lin >> 3);
  const int bx = wg % 24, by = wg / 24;
  const int row0 = by * 128, col0 = bx * 128;
  const u16* Ablk = A + (size_t)row0 * 1024;
  const u16* Bblk = Bt + (size_t)col0 * 1024;
  f32x4 acc[4][4] = {};
  for (int k0 = 0; k0 < 1024; k0 += 64) {
    #pragma unroll
    for (int i = 0; i < 4; i++) {
      int off = (i * 256 + tid) * 16;            // byte in 16KB tile
      int row = off >> 7;
      int cs = (off & 127) ^ ((row & 7) << 4);   // inverse-swizzled source
      GLD16(Ablk + (size_t)row * 1024 + k0 + (cs >> 1), (u16*)As + (off >> 1));
    }
    #pragma unroll
    for (int i = 0; i < 4; i++) {
      int off = (i * 256 + tid) * 16;
      int row = off >> 7;
      int cs = (off & 127) ^ ((row & 7) << 4);
      GLD16(Bblk + (size_t)row * 1024 + k0 + (cs >> 1), (u16*)Bs + (off >> 1));
    }
    __syncthreads();
    #pragma unroll
    for (int kc = 0; kc < 2; kc++) {
      s16x8 xf[4], wf[4];
      #pragma unroll
      for (int m = 0; m < 4; m++) {
        int row = wr * 64 + m * 16 + l15;
        xf[m] = *(const s16x8*)((const char*)As + row * 128 +
                                ((kc * 64 + l4 * 16) ^ ((row & 7) << 4)));
      }
      #pragma unroll
      for (int n = 0; n < 4; n++) {
        int row = wc * 64 + n * 16 + l15;
        wf[n] = *(const s16x8*)((const char*)Bs + row * 128 +
                                ((kc * 64 + l4 * 16) ^ ((row & 7) << 4)));
      }
      #pragma unroll
      for (int m = 0; m < 4; m++)
        #pragma unroll
        for (int n = 0; n < 4; n++)
          acc[m][n] = __builtin_amdgcn_mfma_f32_16x16x32_bf16(wf[n], xf[m], acc[m][n], 0, 0, 0);
    }
    __syncthreads();
  }
  // epilogue: x-row = row0+wr*64+m*16+l15 ; out col = col0+wc*64+n*16+l4*4+i
  const int nng = row0 + wr * 64;
  const int cg0 = col0 + wc * 64;
  #pragma unroll
  for (int n = 0; n < 4; n++) {
    int cb = cg0 + n * 16 + l4 * 4;      // 4 consecutive out cols (same part)
    int h = cb / 192, rr = cb % 192;
    int part = rr >> 6, d = rr & 63;
    u16* dst = (part == 0) ? kb : (part == 1) ? qb : vb;
    float sc = (part == 1) ? 0.125f * 1.44269504f : 1.0f;
    float4 bv = *(const float4*)(bias + h * 192 + rr);
    #pragma unroll
    for (int m = 0; m < 4; m++) {
      int nn = nng + m * 16 + l15;
      int b = nn >> 11, n2 = nn & 2047;
      u16* p = dst + (((size_t)(b * 16 + h) * 2048 + n2) << 6) + d;
      u32x2 w;
      w[0] = cvtpk((acc[m][n][0] + bv.x) * sc, (acc[m][n][1] + bv.y) * sc);
      w[1] = cvtpk((acc[m][n][2] + bv.z) * sc, (acc[m][n][3] + bv.w) * sc);
      *(u32x2*)p = w;
    }
  }
}

// ---------------- OUT GEMM v2: 128x64x64 tiles, T2 swizzle ------------------
// A = sab [4096][1024] bf16, Bt = wot [1024][1024] bf16. 512 blocks (2/CU).
// Standard operand order -> coalesced 64B f32 stores per 16-lane group.
__global__ __launch_bounds__(256) void gemm_out(
    const u16* __restrict__ A, const u16* __restrict__ Bt,
    const float* __restrict__ bias, float* __restrict__ fout) {
  __shared__ __align__(16) u16 As[128 * 64];
  __shared__ __align__(16) u16 Bs[64 * 64];
  const int tid = threadIdx.x;
  const int lane = tid & 63;
  const int w = tid >> 6;               // wave -> 32-row strip
  const int l15 = lane & 15, l4 = lane >> 4;
  // bijective XCD swizzle: 512 = 8 * 64; row-chunks (4 rows of 16) share A
  const int lin = blockIdx.x;
  const int wg = (lin & 7) * 64 + (lin >> 3);
  const int bx = wg & 15, by = wg >> 4;
  const int row0 = by * 128, col0 = bx * 64;
  const u16* Ablk = A + (size_t)row0 * 1024;
  const u16* Bblk = Bt + (size_t)col0 * 1024;
  f32x4 acc[2][4] = {};
  for (int k0 = 0; k0 < 1024; k0 += 64) {
    #pragma unroll
    for (int i = 0; i < 4; i++) {
      int off = (i * 256 + tid) * 16;
      int row = off >> 7;
      int cs = (off & 127) ^ ((row & 7) << 4);
      GLD16(Ablk + (size_t)row * 1024 + k0 + (cs >> 1), (u16*)As + (off >> 1));
    }
    #pragma unroll
    for (int i = 0; i < 2; i++) {
      int off = (i * 256 + tid) * 16;
      int row = off >> 7;
      int cs = (off & 127) ^ ((row & 7) << 4);
      GLD16(Bblk + (size_t)row * 1024 + k0 + (cs >> 1), (u16*)Bs + (off >> 1));
    }
    __syncthreads();
    #pragma unroll
    for (int kc = 0; kc < 2; kc++) {
      s16x8 xf[2], wf[4];
      #pragma unroll
      for (int m = 0; m < 2; m++) {
        int row = w * 32 + m * 16 + l15;
        xf[m] = *(const s16x8*)((const char*)As + row * 128 +
                                ((kc * 64 + l4 * 16) ^ ((row & 7) << 4)));
      }
      #pragma unroll
      for (int n = 0; n < 4; n++) {
        int row = n * 16 + l15;
        wf[n] = *(const s16x8*)((const char*)Bs + row * 128 +
                                ((kc * 64 + l4 * 16) ^ ((row & 7) << 4)));
      }
      #pragma unroll
      for (int m = 0; m < 2; m++)
        #pragma unroll
        for (int n = 0; n < 4; n++)
          acc[m][n] = __builtin_amdgcn_mfma_f32_16x16x32_bf16(xf[m], wf[n], acc[m][n], 0, 0, 0);
    }
    __syncthreads();
  }
  #pragma unroll
  for (int n = 0; n < 4; n++) {
    int c = col0 + n * 16 + l15;
    float bv = bias[c];
    #pragma unroll
    for (int m = 0; m < 2; m++)
      #pragma unroll
      for (int i = 0; i < 4; i++) {
        int r = row0 + w * 32 + m * 16 + l4 * 4 + i;
        fout[(size_t)r * 1024 + c] = acc[m][n][i] + bv;
      }
  }
}

// ---------------- causal flash attention (v7: static pairs + kv-split) ------
__global__ __launch_bounds__(256, 2) void attn_kernel(
    const u16* __restrict__ q, const u16* __restrict__ k,
    const u16* __restrict__ vt, u16* __restrict__ sa) {
  __shared__ __align__(16) u16 Ks[2][64 * 64];
  __shared__ __align__(16) u16 Vs[2][64 * 64];
  __shared__ __align__(16) float Mo[2][64][36];  // per-pair partner O (padded)
  __shared__ float Mml[2][64][2];
  const int tid = threadIdx.x;
  const int lane = tid & 63;
  const int wave = tid >> 6;      // 0..3
  const int p = wave & 1;         // row-half of the 64-row tile
  const int q2 = wave >> 1;       // kv-half of each 64-kv tile
  const int l31 = lane & 31;
  const int h = lane >> 5;

  const int bid = blockIdx.x;
  const int bh = (bid & 7) * 4 + ((bid >> 3) & 3);  // 4 bh per XCD (L2 locality)
  const int j = bid >> 5;                            // 0..15
  const u16* kbh = k + (((size_t)bh * 2048) << 6);
  const u16* vbh = vt + (size_t)bh * 64 * 2048;
  const int b_ = bh >> 4, head = bh & 15;
  const int swz = (l31 & 7) << 4;

  int cur = 0;
  for (int sub = 0; sub < 2; sub++) {
    const int t = sub ? j : (31 - j);
    const int qrow = t * 64 + p * 32 + l31;  // this lane's q row

    // prologue: stage kt=0 into buffer cur (linear dest, inv-swizzled src)
    #pragma unroll
    for (int i = 0; i < 2; i++) {
      int o2 = tid * 16 + i * 4096;
      int row = o2 >> 7;
      int cs = (o2 & 127) ^ ((row & 7) << 4);
      GLD16(kbh + (((size_t)row) << 6) + (cs >> 1), (u16*)Ks[cur] + (o2 >> 1));
      GLD16(vbh + (size_t)row * 2048 + (cs >> 1), (u16*)Vs[cur] + (o2 >> 1));
    }

    // Q B-frags: col = l31 (q-row), k-chunk c: d = c*16 + 8h + j
    const u16* qr = q + (((size_t)bh * 2048 + qrow) << 6);
    s16x8 qf[4];
    #pragma unroll
    for (int c = 0; c < 4; c++)
      qf[c] = *(const s16x8*)(qr + c * 16 + h * 8);

    f32x16 o0 = {}, o1 = {};
    float m_ = -3e38f, l_ = 0.f;

    for (int kt = 0; kt <= t; kt++) {
      if (kt < t) {
        u16* KsB = (u16*)Ks[cur ^ 1];
        u16* VsB = (u16*)Vs[cur ^ 1];
        #pragma unroll
        for (int i = 0; i < 2; i++) {
          int o2 = tid * 16 + i * 4096;
          int row = o2 >> 7;
          int cs = (o2 & 127) ^ ((row & 7) << 4);
          GLD16(kbh + (((size_t)((kt + 1) * 64 + row)) << 6) + (cs >> 1), KsB + (o2 >> 1));
          GLD16(vbh + (size_t)row * 2048 + (kt + 1) * 64 + (cs >> 1), VsB + (o2 >> 1));
        }
        asm volatile("s_waitcnt vmcnt(4)" ::: "memory");
      } else {
        asm volatile("s_waitcnt vmcnt(0)" ::: "memory");
      }
      __builtin_amdgcn_s_barrier();
      __builtin_amdgcn_sched_barrier(0);

      // wave fully masked only on diag tile, upper-kv x lower-row
      const bool active = !(kt == t && q2 == 1 && p == 0);
      if (active) {
        const char* Kc = (const char*)Ks[cur];
        const char* Vc = (const char*)Vs[cur];
        // S^T = K_half * Q^T : A rows kv = q2*32 + l31
        f32x16 s0 = {};
        __builtin_amdgcn_s_setprio(1);
        #pragma unroll
        for (int c = 0; c < 4; c++) {
          s16x8 kf = *(const s16x8*)(Kc + (q2 * 32 + l31) * 128 + ((c * 32 + 16 * h) ^ swz));
          s0 = __builtin_amdgcn_mfma_f32_32x32x16_bf16(kf, qf[c], s0, 0, 0, 0);
        }
        __builtin_amdgcn_s_setprio(0);

        // causal mask (diag tile only): kv = kt*64 + q2*32 + (r&3)+8*(r>>2)+4h
        if (kt == t) {
          int kvb = t * 64 + q2 * 32 + 4 * h;
          #pragma unroll
          for (int r = 0; r < 16; r++)
            if (kvb + (r & 3) + 8 * (r >> 2) > qrow) s0[r] = -3e38f;
        }

        // in-register online softmax (exp2 domain), T13 defer-rescale
        float pmax = s0[0];
        #pragma unroll
        for (int r = 1; r < 16; r++) pmax = fmaxf(pmax, s0[r]);
        pmax = fmaxf(pmax, __shfl_xor(pmax, 32));
        bool need = pmax > m_ + 11.f;
        if (__any((int)need)) {
          float mn = fmaxf(m_, pmax);
          float al = exp2f(m_ - mn);
          m_ = mn;
          l_ *= al;
          #pragma unroll
          for (int r = 0; r < 16; r++) { o0[r] *= al; o1[r] *= al; }
        }
        float rs = 0.f;
        #pragma unroll
        for (int r = 0; r < 16; r++) {
          float pv = exp2f(s0[r] - m_);
          s0[r] = pv;
          rs += pv;
        }
        rs += __shfl_xor(rs, 32);
        l_ += rs;

        // P -> bf16 B-frags (cvt_pk + half-swap exchange)
        uint32_t pk[8];
        #pragma unroll
        for (int g = 0; g < 8; g++)
          pk[g] = cvtpk(s0[2 * g], s0[2 * g + 1]);
        s16x8 pf[2];
        #pragma unroll
        for (int ss = 0; ss < 2; ss++) {
          uint32_t sendA = h ? pk[4 * ss + 0] : pk[4 * ss + 2];
          uint32_t sendB = h ? pk[4 * ss + 1] : pk[4 * ss + 3];
          uint32_t rA = (uint32_t)__shfl_xor((int)sendA, 32);
          uint32_t rB = (uint32_t)__shfl_xor((int)sendB, 32);
          u32x4 w2;
          w2[0] = h ? rA : pk[4 * ss + 0];
          w2[1] = h ? rB : pk[4 * ss + 1];
          w2[2] = h ? pk[4 * ss + 2] : rA;
          w2[3] = h ? pk[4 * ss + 3] : rB;
          pf[ss] = __builtin_bit_cast(s16x8, w2);
        }

        // O^T += V^T_half * P^T
        __builtin_amdgcn_s_setprio(1);
        #pragma unroll
        for (int ss = 0; ss < 2; ss++) {
          s16x8 vf0 = *(const s16x8*)(Vc + l31 * 128 + ((q2 * 64 + ss * 32 + 16 * h) ^ swz));
          s16x8 vf1 = *(const s16x8*)(Vc + (32 + l31) * 128 + ((q2 * 64 + ss * 32 + 16 * h) ^ swz));
          o0 = __builtin_amdgcn_mfma_f32_32x32x16_bf16(vf0, pf[ss], o0, 0, 0, 0);
          o1 = __builtin_amdgcn_mfma_f32_32x32x16_bf16(vf1, pf[ss], o1, 0, 0, 0);
        }
        __builtin_amdgcn_s_setprio(0);
      }
      __builtin_amdgcn_sched_barrier(0);
      __builtin_amdgcn_s_barrier();  // protect consumed buffer from restage
      cur ^= 1;
    }

    // ----- merge kv-halves (waves q2=1 -> LDS; waves q2=0 combine + store) ----
    if (q2) {
      float4* dst = (float4*)&Mo[p][lane][0];
      #pragma unroll
      for (int c = 0; c < 4; c++) {
        f32x4 a = {o0[4 * c], o0[4 * c + 1], o0[4 * c + 2], o0[4 * c + 3]};
        f32x4 b = {o1[4 * c], o1[4 * c + 1], o1[4 * c + 2], o1[4 * c + 3]};
        dst[c] = __builtin_bit_cast(float4, a);
        dst[4 + c] = __builtin_bit_cast(float4, b);
      }
      Mml[p][lane][0] = m_;
      Mml[p][lane][1] = l_;
    }
    __syncthreads();
    if (!q2) {
      float mB = Mml[p][lane][0], lB = Mml[p][lane][1];
      float ob[32];
      #pragma unroll
      for (int c = 0; c < 8; c++) {
        float4 v = ((const float4*)&Mo[p][lane][0])[c];
        ob[4 * c] = v.x; ob[4 * c + 1] = v.y; ob[4 * c + 2] = v.z; ob[4 * c + 3] = v.w;
      }
      float mS = fmaxf(m_, mB);
      float aA = exp2f(m_ - mS), aB = exp2f(mB - mS);
      float inv = 1.f / (l_ * aA + lB * aB);
      u16* dst = sa + ((size_t)(b_ * 2048 + qrow) << 10) + head * 64;
      #pragma unroll
      for (int i = 0; i < 8; i++) {
        int r = 2 * i;
        int d = (r & 3) + 8 * (r >> 2) + 4 * h;
        float v0 = (o0[r] * aA + ob[r] * aB) * inv;
        float v1 = (o0[r + 1] * aA + ob[r + 1] * aB) * inv;
        *(uint32_t*)(dst + d) = cvtpk(v0, v1);
        float w0 = (o1[r] * aA + ob[16 + r] * aB) * inv;
        float w1 = (o1[r + 1] * aA + ob[16 + r + 1] * aB) * inv;
        *(uint32_t*)(dst + d + 32) = cvtpk(w0, w1);
      }
    }
    __syncthreads();  // merge region reusable; stores drain here too
  }
}

extern "C" void kernel_launch(void* const* d_in, const int* in_sizes, int n_in,
                              void* d_out, int out_size, void* d_ws, size_t ws_size,
                              hipStream_t stream) {
  const float* x    = (const float*)d_in[0];
  const float* Wqkv = (const float*)d_in[1];
  const float* bqkv = (const float*)d_in[2];
  const float* Wo   = (const float*)d_in[3];
  const float* bo   = (const float*)d_in[4];
  float* out = (float*)d_out;

  // workspace carve (u16 elements)
  u16* xb  = (u16*)d_ws;          // [4096][1024] (reused as sab after qkv gemm)
  u16* wqt = xb + 4194304;        // [16*192][1024]
  u16* wot = wqt + 3145728;       // [1024][1024]
  u16* qb  = wot + 1048576;       // [32][2048][64]
  u16* kb  = qb + 4194304;
  u16* vb  = kb + 4194304;        // [32][2048][64]
  u16* vtb = vb + 4194304;        // [32][64][2048]
  u16* sab = xb;                  // alias: x's bf16 copy dead after qkv gemm

  cvt_kernel<<<2048, 256, 0, stream>>>(x, xb);
  transpose_f2b<<<dim3(6, 32, 16), dim3(32, 8), 0, stream>>>(Wqkv, wqt, 1024, 192);
  transpose_f2b<<<dim3(32, 32, 1), dim3(32, 8), 0, stream>>>(Wo, wot, 1024, 1024);
  gemm_qkv<<<dim3(768), 256, 0, stream>>>(xb, wqt, bqkv, kb, qb, vb);
  transpose_b2b<<<dim3(2, 64, 32), dim3(32, 8), 0, stream>>>(vb, vtb, 2048, 64);
  attn_kernel<<<dim3(512), 256, 0, stream>>>(qb, kb, vtb, sab);
  gemm_out<<<dim3(512), 256, 0, stream>>>(sab, wot, bo, out);
}